// Round 4
// baseline (158.785 us; speedup 1.0000x reference)
//
#include <hip/hip_runtime.h>
#include <hip/hip_bf16.h>

// x (16,1024,512) fp32 -> d = max(0, sq_i+sq_j-2*X X^T) per batch
// -> global-mean/var LayerNorm -> softmax(-(d_hat*gamma+beta)/TEMP, axis=-1).
// Softmax is shift-invariant => mean & beta cancel; only
// scale = gamma*rsqrt(var+eps)/TEMP survives. var needs global sum(d),sum(d^2)
// in f64 (E[d^2]~1.05e6 vs var~4e3 -> cancellation).
// Softmax is ALSO row-shift-invariant => store d' = d - sq_row as fp16
// (range ~±900..3500, ulp err * scale * p_max ~ 4e-6 in output: safe).
//
// Pipeline: (1) sqcvt: x->bf16 (ws) + row sq + zero sums
//           (2) gram3: MFMA GEMM, 2-phase double-buffered global_load_lds w16
//               (prefetch k+1 BEFORE compute of k; one vmcnt(0)+barrier/step),
//               XOR-swizzled LDS (pre-swizzled global source), XCD-aware block
//               map, fused d-epilogue + f64 sum reduction
//           (3) softmax: one row per wave, no barriers.

#define S_DIM 1024
#define E_DIM 512
#define NBATCH 16
#define TEMP_C 13.544

typedef __attribute__((ext_vector_type(4))) float f32x4;
typedef __attribute__((ext_vector_type(8))) short bf16x8;
typedef __attribute__((ext_vector_type(8))) _Float16 f16x8;

__device__ inline unsigned pkbf(float lo, float hi) {
  unsigned a = __float_as_uint(lo), b = __float_as_uint(hi);
  a = (a + 0x7FFFu + ((a >> 16) & 1u)) >> 16;          // RNE bf16 of lo
  b = (b + 0x7FFFu + ((b >> 16) & 1u)) & 0xFFFF0000u;  // RNE bf16 of hi << 16
  return b | a;
}

__device__ inline void gload16(const void* g, void* l) {
  __builtin_amdgcn_global_load_lds(
      (const __attribute__((address_space(1))) unsigned*)g,
      (__attribute__((address_space(3))) unsigned*)l, 16, 0, 0);
}

// ---------------- Kernel 1: fp32->bf16 convert + row square-sums ------------
__global__ __launch_bounds__(256) void sqcvt(const float* __restrict__ x,
                                             ushort* __restrict__ xb16,
                                             float* __restrict__ sq,
                                             double* __restrict__ sums) {
  const int wave = threadIdx.x >> 6, lane = threadIdx.x & 63;
  const size_t row = (size_t)blockIdx.x * 4 + wave;
  const float4* xr = reinterpret_cast<const float4*>(x + row * E_DIM);
  float4 a = xr[lane * 2], b = xr[lane * 2 + 1];
  uint4 p;
  p.x = pkbf(a.x, a.y); p.y = pkbf(a.z, a.w);
  p.z = pkbf(b.x, b.y); p.w = pkbf(b.z, b.w);
  *reinterpret_cast<uint4*>(xb16 + row * E_DIM + lane * 8) = p;
  float s = a.x*a.x + a.y*a.y + a.z*a.z + a.w*a.w +
            b.x*b.x + b.y*b.y + b.z*b.z + b.w*b.w;
#pragma unroll
  for (int o = 32; o > 0; o >>= 1) s += __shfl_xor(s, o);
  if (lane == 0) sq[row] = s;
  if (blockIdx.x == 0 && threadIdx.x == 0) { sums[0] = 0.0; sums[1] = 0.0; }
}

// ---------------- Kernel 2: gram via bf16 MFMA, 2-phase pipelined -----------
// 128x128 tile, BK=32, 4 waves (2x2). global_load_lds w16, double-buffered:
// issue stage(k+1) BEFORE ds_read/MFMA of k, single vmcnt(0)+barrier per step.
// XOR-swizzle ((row>>1)&3 on 16B slot) on global source AND ds_read (rule 21).
// MODE 0: write d fp32 to dout. MODE 1: write d'=d-sq_row fp16 to dp.
template <int MODE>
__global__ __launch_bounds__(256) void gram3(const ushort* __restrict__ xb16,
                                             const float* __restrict__ sq,
                                             float* __restrict__ dout,
                                             _Float16* __restrict__ dp,
                                             double* __restrict__ sums) {
  __shared__ ushort lA[2][4096];
  __shared__ ushort lB[2][4096];
  __shared__ double red[8];

  const int tid = threadIdx.x, wave = tid >> 6, lane = tid & 63;
  const int wr = wave >> 1, wc = wave & 1;

  // XCD-aware map: xcd = bid&7, 2 batches per XCD -> 1 MB slab L2-resident.
  const int bid = blockIdx.x;
  const int xcd = bid & 7, li = bid >> 3;
  const int b = (xcd << 1) | (li >> 6);
  const int tile = li & 63;
  const int tr = tile >> 3, tc = tile & 7;

  const ushort* xb = xb16 + (size_t)b * (S_DIM * E_DIM);
  const int rowA0 = tr * 128, rowB0 = tc * 128;

  // Pre-swizzled per-lane global element offsets (LDS dest is linear).
  int eA[2], eB[2];
  const int o0 = wave * 1024 + lane * 16;
#pragma unroll
  for (int i = 0; i < 2; ++i) {
    int o = o0 + i * 4096;
    int so = o ^ (((o >> 7) & 3) << 4);
    int row = so >> 6, cb = (so >> 4) & 3;
    eA[i] = (rowA0 + row) * E_DIM + cb * 8;
    eB[i] = (rowB0 + row) * E_DIM + cb * 8;
  }

  auto stage = [&](int buf, int k0) {
    char* la = (char*)&lA[buf][0];
    char* lb = (char*)&lB[buf][0];
    gload16(xb + eA[0] + k0, la + wave * 1024);
    gload16(xb + eA[1] + k0, la + 4096 + wave * 1024);
    gload16(xb + eB[0] + k0, lb + wave * 1024);
    gload16(xb + eB[1] + k0, lb + 4096 + wave * 1024);
  };

  f32x4 acc[4][4] = {};

  stage(0, 0);
  __syncthreads();
  int buf = 0;
#pragma unroll 1
  for (int ks = 0; ks < E_DIM / 32; ++ks) {
    if (ks + 1 < E_DIM / 32) stage(buf ^ 1, (ks + 1) * 32);  // prefetch FIRST
    bf16x8 af[4], bfr[4];
    const int cb = lane >> 4;
    const char* la = (const char*)&lA[buf][0];
    const char* lb = (const char*)&lB[buf][0];
#pragma unroll
    for (int m = 0; m < 4; ++m) {
      int row = wr * 64 + m * 16 + (lane & 15);
      af[m] = *reinterpret_cast<const bf16x8*>(la + row * 64 + ((cb ^ ((row >> 1) & 3)) << 4));
    }
#pragma unroll
    for (int n = 0; n < 4; ++n) {
      int row = wc * 64 + n * 16 + (lane & 15);
      bfr[n] = *reinterpret_cast<const bf16x8*>(lb + row * 64 + ((cb ^ ((row >> 1) & 3)) << 4));
    }
#pragma unroll
    for (int m = 0; m < 4; ++m)
#pragma unroll
      for (int n = 0; n < 4; ++n)
        acc[m][n] = __builtin_amdgcn_mfma_f32_16x16x32_bf16(af[m], bfr[n], acc[m][n], 0, 0, 0);
    __syncthreads();   // drains vmcnt(0): prefetched buf^1 ready; reads of buf done
    buf ^= 1;
  }

  // Epilogue. C/D layout: col=lane&15, row=(lane>>4)*4+reg.
  const float* sqb = sq + b * S_DIM;
  double sd = 0.0, sd2 = 0.0;
#pragma unroll
  for (int m = 0; m < 4; ++m) {
    int gr0 = tr * 128 + wr * 64 + m * 16 + ((lane >> 4) << 2);
    float sqr0 = sqb[gr0], sqr1 = sqb[gr0 + 1], sqr2 = sqb[gr0 + 2], sqr3 = sqb[gr0 + 3];
#pragma unroll
    for (int n = 0; n < 4; ++n) {
      int gc = tc * 128 + wc * 64 + n * 16 + (lane & 15);
      float sqc = sqb[gc];
      float d0 = fmaxf(sqr0 + sqc - 2.0f * acc[m][n][0], 0.0f);
      float d1 = fmaxf(sqr1 + sqc - 2.0f * acc[m][n][1], 0.0f);
      float d2 = fmaxf(sqr2 + sqc - 2.0f * acc[m][n][2], 0.0f);
      float d3 = fmaxf(sqr3 + sqc - 2.0f * acc[m][n][3], 0.0f);
      if (MODE == 0) {
        float* dbase = dout + (size_t)b * S_DIM * S_DIM;
        dbase[(size_t)(gr0 + 0) * S_DIM + gc] = d0;
        dbase[(size_t)(gr0 + 1) * S_DIM + gc] = d1;
        dbase[(size_t)(gr0 + 2) * S_DIM + gc] = d2;
        dbase[(size_t)(gr0 + 3) * S_DIM + gc] = d3;
      } else {
        _Float16* dbase = dp + (size_t)b * S_DIM * S_DIM;
        dbase[(size_t)(gr0 + 0) * S_DIM + gc] = (_Float16)(d0 - sqr0);
        dbase[(size_t)(gr0 + 1) * S_DIM + gc] = (_Float16)(d1 - sqr1);
        dbase[(size_t)(gr0 + 2) * S_DIM + gc] = (_Float16)(d2 - sqr2);
        dbase[(size_t)(gr0 + 3) * S_DIM + gc] = (_Float16)(d3 - sqr3);
      }
      sd += (double)d0 + (double)d1 + (double)d2 + (double)d3;
      sd2 += (double)d0 * d0 + (double)d1 * d1 + (double)d2 * d2 + (double)d3 * d3;
    }
  }
#pragma unroll
  for (int o = 32; o > 0; o >>= 1) {
    sd += __shfl_xor(sd, o);
    sd2 += __shfl_xor(sd2, o);
  }
  if (lane == 0) { red[wave] = sd; red[4 + wave] = sd2; }
  __syncthreads();
  if (tid == 0) {
    atomicAdd(&sums[0], red[0] + red[1] + red[2] + red[3]);
    atomicAdd(&sums[1], red[4] + red[5] + red[6] + red[7]);
  }
}

__device__ inline float ln_scale(const double* sums, const float* gamma) {
  constexpr double invN = 1.0 / (16.0 * 1024.0 * 1024.0);
  double mean = sums[0] * invN;
  double var = sums[1] * invN - mean * mean;
  return (float)(-((double)gamma[0]) / (sqrt(var + 1e-5) * TEMP_C));
}

// ---------------- Kernel 3a: softmax from fp32 d (in-place in dout) ---------
__global__ __launch_bounds__(256) void softmax_f32(float* __restrict__ d,
                                                   const double* __restrict__ sums,
                                                   const float* __restrict__ gamma) {
  const int wave = threadIdx.x >> 6, lane = threadIdx.x & 63;
  const size_t row = (size_t)blockIdx.x * 4 + wave;
  const float scale = ln_scale(sums, gamma);
  float4* r4 = reinterpret_cast<float4*>(d + row * S_DIM);
  float4 v[4];
#pragma unroll
  for (int i = 0; i < 4; ++i) v[i] = r4[lane + 64 * i];
  float l[16];
#pragma unroll
  for (int i = 0; i < 4; ++i) {
    l[4*i+0] = scale * v[i].x; l[4*i+1] = scale * v[i].y;
    l[4*i+2] = scale * v[i].z; l[4*i+3] = scale * v[i].w;
  }
  float mx = l[0];
#pragma unroll
  for (int i = 1; i < 16; ++i) mx = fmaxf(mx, l[i]);
#pragma unroll
  for (int o = 32; o > 0; o >>= 1) mx = fmaxf(mx, __shfl_xor(mx, o));
  const float L2E = 1.4426950408889634f;
  float e[16], s = 0.f;
#pragma unroll
  for (int i = 0; i < 16; ++i) { e[i] = exp2f((l[i] - mx) * L2E); s += e[i]; }
#pragma unroll
  for (int o = 32; o > 0; o >>= 1) s += __shfl_xor(s, o);
  float inv = 1.0f / s;
#pragma unroll
  for (int i = 0; i < 4; ++i)
    r4[lane + 64 * i] = make_float4(e[4*i]*inv, e[4*i+1]*inv, e[4*i+2]*inv, e[4*i+3]*inv);
}

// ---------------- Kernel 3b: softmax from fp16 d' (ws) -> fp32 out ----------
__global__ __launch_bounds__(256) void softmax_f16(const _Float16* __restrict__ dp,
                                                   float* __restrict__ out,
                                                   const double* __restrict__ sums,
                                                   const float* __restrict__ gamma) {
  const int wave = threadIdx.x >> 6, lane = threadIdx.x & 63;
  const size_t row = (size_t)blockIdx.x * 4 + wave;
  const float scale = ln_scale(sums, gamma);
  const f16x8* r8 = reinterpret_cast<const f16x8*>(dp + row * S_DIM);
  f16x8 h0 = r8[lane * 2], h1 = r8[lane * 2 + 1];
  float l[16];
#pragma unroll
  for (int i = 0; i < 8; ++i) { l[i] = scale * (float)h0[i]; l[8 + i] = scale * (float)h1[i]; }
  float mx = l[0];
#pragma unroll
  for (int i = 1; i < 16; ++i) mx = fmaxf(mx, l[i]);
#pragma unroll
  for (int o = 32; o > 0; o >>= 1) mx = fmaxf(mx, __shfl_xor(mx, o));
  const float L2E = 1.4426950408889634f;
  float e[16], s = 0.f;
#pragma unroll
  for (int i = 0; i < 16; ++i) { e[i] = exp2f((l[i] - mx) * L2E); s += e[i]; }
#pragma unroll
  for (int o = 32; o > 0; o >>= 1) s += __shfl_xor(s, o);
  float inv = 1.0f / s;
  float4* o4 = reinterpret_cast<float4*>(out + row * S_DIM);
#pragma unroll
  for (int i = 0; i < 4; ++i)
    o4[lane * 4 + i] = make_float4(e[4*i]*inv, e[4*i+1]*inv, e[4*i+2]*inv, e[4*i+3]*inv);
}

extern "C" void kernel_launch(void* const* d_in, const int* in_sizes, int n_in,
                              void* d_out, int out_size, void* d_ws, size_t ws_size,
                              hipStream_t stream) {
  const float* x = (const float*)d_in[0];
  const float* gamma = (const float*)d_in[1];
  float* out = (float*)d_out;
  double* sums = (double*)d_ws;                              // 2 doubles @0
  float* sq = (float*)((char*)d_ws + 256);                   // 16384 floats
  ushort* xb16 = (ushort*)((char*)d_ws + 256 + 65536);       // 16 MB bf16 x
  _Float16* dp = (_Float16*)((char*)d_ws + 256 + 65536 +
                             (size_t)NBATCH * S_DIM * E_DIM * 2);  // 32 MB fp16 d'
  const size_t need_b = 256 + 65536 + (size_t)NBATCH * S_DIM * E_DIM * 2;
  const size_t need_a = need_b + (size_t)NBATCH * S_DIM * S_DIM * 2;

  sqcvt<<<dim3(NBATCH * S_DIM / 4), dim3(256), 0, stream>>>(x, xb16, sq, sums);
  if (ws_size >= need_a) {
    gram3<1><<<dim3(NBATCH * 64), dim3(256), 0, stream>>>(xb16, sq, out, dp, sums);
    softmax_f16<<<dim3(NBATCH * S_DIM / 4), dim3(256), 0, stream>>>(dp, out, sums, gamma);
  } else {
    gram3<0><<<dim3(NBATCH * 64), dim3(256), 0, stream>>>(xb16, sq, out, dp, sums);
    softmax_f32<<<dim3(NBATCH * S_DIM / 4), dim3(256), 0, stream>>>(out, sums, gamma);
  }
}

// Round 5
// 158.661 us; speedup vs baseline: 1.0008x; 1.0008x over previous
//
#include <hip/hip_runtime.h>
#include <hip/hip_bf16.h>

// x (16,1024,512) fp32 -> d = max(0, sq_i+sq_j-2*X X^T) per batch
// -> global-mean/var LayerNorm -> softmax(-(d_hat*gamma+beta)/TEMP, axis=-1).
// Softmax shift-invariance => mean & beta cancel; only
// scale = gamma*rsqrt(var+eps)/TEMP survives. var needs global sum(d),sum(d^2)
// in f64 (E[d^2]~1.05e6 vs var~4e3 -> cancellation).
// Row-shift-invariance => store d' = d - sq_row as fp16 (err ~4e-6 in out).
//
// gram4: depth-2 prefetch, 3 LDS buffers, counted vmcnt(4) + ONE raw
// s_barrier per K-step (loads stay in flight across barriers, T3/T4-lite).

#define S_DIM 1024
#define E_DIM 512
#define NBATCH 16
#define NSTEP (E_DIM / 32)
#define TEMP_C 13.544

typedef __attribute__((ext_vector_type(4))) float f32x4;
typedef __attribute__((ext_vector_type(8))) short bf16x8;
typedef __attribute__((ext_vector_type(8))) _Float16 f16x8;

__device__ inline unsigned pkbf(float lo, float hi) {
  unsigned a = __float_as_uint(lo), b = __float_as_uint(hi);
  a = (a + 0x7FFFu + ((a >> 16) & 1u)) >> 16;          // RNE bf16 of lo
  b = (b + 0x7FFFu + ((b >> 16) & 1u)) & 0xFFFF0000u;  // RNE bf16 of hi << 16
  return b | a;
}

__device__ inline void gload16(const void* g, void* l) {
  __builtin_amdgcn_global_load_lds(
      (const __attribute__((address_space(1))) unsigned*)g,
      (__attribute__((address_space(3))) unsigned*)l, 16, 0, 0);
}

// ---------------- Kernel 1: fp32->bf16 convert + row square-sums ------------
__global__ __launch_bounds__(256) void sqcvt(const float* __restrict__ x,
                                             ushort* __restrict__ xb16,
                                             float* __restrict__ sq,
                                             double* __restrict__ sums) {
  const int wave = threadIdx.x >> 6, lane = threadIdx.x & 63;
  const size_t row = (size_t)blockIdx.x * 4 + wave;
  const float4* xr = reinterpret_cast<const float4*>(x + row * E_DIM);
  float4 a = xr[lane * 2], b = xr[lane * 2 + 1];
  uint4 p;
  p.x = pkbf(a.x, a.y); p.y = pkbf(a.z, a.w);
  p.z = pkbf(b.x, b.y); p.w = pkbf(b.z, b.w);
  *reinterpret_cast<uint4*>(xb16 + row * E_DIM + lane * 8) = p;
  float s = a.x*a.x + a.y*a.y + a.z*a.z + a.w*a.w +
            b.x*b.x + b.y*b.y + b.z*b.z + b.w*b.w;
#pragma unroll
  for (int o = 32; o > 0; o >>= 1) s += __shfl_xor(s, o);
  if (lane == 0) sq[row] = s;
  if (blockIdx.x == 0 && threadIdx.x == 0) { sums[0] = 0.0; sums[1] = 0.0; }
}

// ------- Kernel 2: gram via bf16 MFMA, depth-2 pipelined, counted vmcnt -----
// 128x128 tile, BK=32, 4 waves (2x2). 3 buffers; iter k: wait own vmcnt(4)
// (stage(k) landed; stage(k+1) in flight), raw s_barrier, issue stage(k+2),
// ds_read buf k%3, 16 MFMA. XOR-swizzle on global source AND ds_read.
// MODE 0: d fp32 -> dout.  MODE 1: d' = d - sq_row fp16 -> dp.
template <int MODE>
__global__ __launch_bounds__(256) void gram4(const ushort* __restrict__ xb16,
                                             const float* __restrict__ sq,
                                             float* __restrict__ dout,
                                             _Float16* __restrict__ dp,
                                             double* __restrict__ sums) {
  __shared__ ushort lA[3][4096];
  __shared__ ushort lB[3][4096];
  __shared__ double red[8];

  const int tid = threadIdx.x, wave = tid >> 6, lane = tid & 63;
  const int wr = wave >> 1, wc = wave & 1;

  // XCD-aware map: xcd = bid&7, 2 batches per XCD -> 1 MB slab L2-resident.
  const int bid = blockIdx.x;
  const int xcd = bid & 7, li = bid >> 3;
  const int b = (xcd << 1) | (li >> 6);
  const int tile = li & 63;
  const int tr = tile >> 3, tc = tile & 7;

  const ushort* xb = xb16 + (size_t)b * (S_DIM * E_DIM);
  const int rowA0 = tr * 128, rowB0 = tc * 128;

  // Pre-swizzled per-lane global element offsets (LDS dest is linear).
  int eA[2], eB[2];
  const int o0 = wave * 1024 + lane * 16;
#pragma unroll
  for (int i = 0; i < 2; ++i) {
    int o = o0 + i * 4096;
    int so = o ^ (((o >> 7) & 3) << 4);
    int row = so >> 6, cb = (so >> 4) & 3;
    eA[i] = (rowA0 + row) * E_DIM + cb * 8;
    eB[i] = (rowB0 + row) * E_DIM + cb * 8;
  }

  auto stage = [&](int buf, int k0) {
    char* la = (char*)&lA[buf][0];
    char* lb = (char*)&lB[buf][0];
    gload16(xb + eA[0] + k0, la + wave * 1024);
    gload16(xb + eA[1] + k0, la + 4096 + wave * 1024);
    gload16(xb + eB[0] + k0, lb + wave * 1024);
    gload16(xb + eB[1] + k0, lb + 4096 + wave * 1024);
  };

  f32x4 acc[4][4] = {};

  stage(0, 0);
  stage(1, 32);
  int cur = 0;
#pragma unroll 1
  for (int ks = 0; ks < NSTEP; ++ks) {
    // Own stage(k) landed; stage(k+1)'s 4 loads may remain in flight.
    if (ks < NSTEP - 1) {
      asm volatile("s_waitcnt vmcnt(4)" ::: "memory");
    } else {
      asm volatile("s_waitcnt vmcnt(0)" ::: "memory");
    }
    __builtin_amdgcn_s_barrier();   // all waves' stage(k) landed; iter k-1 reads done
    __builtin_amdgcn_sched_barrier(0);
    if (ks + 2 < NSTEP) {
      int nb = cur + 2; if (nb >= 3) nb -= 3;
      stage(nb, (ks + 2) * 32);     // WAR-safe: buf was consumed at iter k-1
    }
    __builtin_amdgcn_sched_barrier(0);

    bf16x8 af[4], bfr[4];
    const int cb = lane >> 4;
    const char* la = (const char*)&lA[cur][0];
    const char* lb = (const char*)&lB[cur][0];
#pragma unroll
    for (int m = 0; m < 4; ++m) {
      int row = wr * 64 + m * 16 + (lane & 15);
      af[m] = *reinterpret_cast<const bf16x8*>(la + row * 64 + ((cb ^ ((row >> 1) & 3)) << 4));
    }
#pragma unroll
    for (int n = 0; n < 4; ++n) {
      int row = wc * 64 + n * 16 + (lane & 15);
      bfr[n] = *reinterpret_cast<const bf16x8*>(lb + row * 64 + ((cb ^ ((row >> 1) & 3)) << 4));
    }
#pragma unroll
    for (int m = 0; m < 4; ++m)
#pragma unroll
      for (int n = 0; n < 4; ++n)
        acc[m][n] = __builtin_amdgcn_mfma_f32_16x16x32_bf16(af[m], bfr[n], acc[m][n], 0, 0, 0);

    if (++cur >= 3) cur = 0;
  }

  // Epilogue. C/D layout: col=lane&15, row=(lane>>4)*4+reg.
  const float* sqb = sq + b * S_DIM;
  double sd = 0.0, sd2 = 0.0;
#pragma unroll
  for (int m = 0; m < 4; ++m) {
    int gr0 = tr * 128 + wr * 64 + m * 16 + ((lane >> 4) << 2);
    float sqr0 = sqb[gr0], sqr1 = sqb[gr0 + 1], sqr2 = sqb[gr0 + 2], sqr3 = sqb[gr0 + 3];
#pragma unroll
    for (int n = 0; n < 4; ++n) {
      int gc = tc * 128 + wc * 64 + n * 16 + (lane & 15);
      float sqc = sqb[gc];
      float d0 = fmaxf(sqr0 + sqc - 2.0f * acc[m][n][0], 0.0f);
      float d1 = fmaxf(sqr1 + sqc - 2.0f * acc[m][n][1], 0.0f);
      float d2 = fmaxf(sqr2 + sqc - 2.0f * acc[m][n][2], 0.0f);
      float d3 = fmaxf(sqr3 + sqc - 2.0f * acc[m][n][3], 0.0f);
      if (MODE == 0) {
        float* dbase = dout + (size_t)b * S_DIM * S_DIM;
        dbase[(size_t)(gr0 + 0) * S_DIM + gc] = d0;
        dbase[(size_t)(gr0 + 1) * S_DIM + gc] = d1;
        dbase[(size_t)(gr0 + 2) * S_DIM + gc] = d2;
        dbase[(size_t)(gr0 + 3) * S_DIM + gc] = d3;
      } else {
        _Float16* dbase = dp + (size_t)b * S_DIM * S_DIM;
        dbase[(size_t)(gr0 + 0) * S_DIM + gc] = (_Float16)(d0 - sqr0);
        dbase[(size_t)(gr0 + 1) * S_DIM + gc] = (_Float16)(d1 - sqr1);
        dbase[(size_t)(gr0 + 2) * S_DIM + gc] = (_Float16)(d2 - sqr2);
        dbase[(size_t)(gr0 + 3) * S_DIM + gc] = (_Float16)(d3 - sqr3);
      }
      sd += (double)d0 + (double)d1 + (double)d2 + (double)d3;
      sd2 += (double)d0 * d0 + (double)d1 * d1 + (double)d2 * d2 + (double)d3 * d3;
    }
  }
#pragma unroll
  for (int o = 32; o > 0; o >>= 1) {
    sd += __shfl_xor(sd, o);
    sd2 += __shfl_xor(sd2, o);
  }
  if (lane == 0) { red[wave] = sd; red[4 + wave] = sd2; }
  __syncthreads();
  if (tid == 0) {
    atomicAdd(&sums[0], red[0] + red[1] + red[2] + red[3]);
    atomicAdd(&sums[1], red[4] + red[5] + red[6] + red[7]);
  }
}

__device__ inline float ln_scale(const double* sums, const float* gamma) {
  constexpr double invN = 1.0 / (16.0 * 1024.0 * 1024.0);
  double mean = sums[0] * invN;
  double var = sums[1] * invN - mean * mean;
  return (float)(-((double)gamma[0]) / (sqrt(var + 1e-5) * TEMP_C));
}

// ---------------- Kernel 3a: softmax from fp32 d (in-place in dout) ---------
__global__ __launch_bounds__(256) void softmax_f32(float* __restrict__ d,
                                                   const double* __restrict__ sums,
                                                   const float* __restrict__ gamma) {
  const int wave = threadIdx.x >> 6, lane = threadIdx.x & 63;
  const size_t row = (size_t)blockIdx.x * 4 + wave;
  const float scale = ln_scale(sums, gamma);
  float4* r4 = reinterpret_cast<float4*>(d + row * S_DIM);
  float4 v[4];
#pragma unroll
  for (int i = 0; i < 4; ++i) v[i] = r4[lane + 64 * i];
  float l[16];
#pragma unroll
  for (int i = 0; i < 4; ++i) {
    l[4*i+0] = scale * v[i].x; l[4*i+1] = scale * v[i].y;
    l[4*i+2] = scale * v[i].z; l[4*i+3] = scale * v[i].w;
  }
  float mx = l[0];
#pragma unroll
  for (int i = 1; i < 16; ++i) mx = fmaxf(mx, l[i]);
#pragma unroll
  for (int o = 32; o > 0; o >>= 1) mx = fmaxf(mx, __shfl_xor(mx, o));
  const float L2E = 1.4426950408889634f;
  float e[16], s = 0.f;
#pragma unroll
  for (int i = 0; i < 16; ++i) { e[i] = exp2f((l[i] - mx) * L2E); s += e[i]; }
#pragma unroll
  for (int o = 32; o > 0; o >>= 1) s += __shfl_xor(s, o);
  float inv = 1.0f / s;
#pragma unroll
  for (int i = 0; i < 4; ++i)
    r4[lane + 64 * i] = make_float4(e[4*i]*inv, e[4*i+1]*inv, e[4*i+2]*inv, e[4*i+3]*inv);
}

// ---------------- Kernel 3b: softmax from fp16 d' (ws) -> fp32 out ----------
__global__ __launch_bounds__(256) void softmax_f16(const _Float16* __restrict__ dp,
                                                   float* __restrict__ out,
                                                   const double* __restrict__ sums,
                                                   const float* __restrict__ gamma) {
  const int wave = threadIdx.x >> 6, lane = threadIdx.x & 63;
  const size_t row = (size_t)blockIdx.x * 4 + wave;
  const float scale = ln_scale(sums, gamma);
  const f16x8* r8 = reinterpret_cast<const f16x8*>(dp + row * S_DIM);
  f16x8 h0 = r8[lane * 2], h1 = r8[lane * 2 + 1];
  float l[16];
#pragma unroll
  for (int i = 0; i < 8; ++i) { l[i] = scale * (float)h0[i]; l[8 + i] = scale * (float)h1[i]; }
  float mx = l[0];
#pragma unroll
  for (int i = 1; i < 16; ++i) mx = fmaxf(mx, l[i]);
#pragma unroll
  for (int o = 32; o > 0; o >>= 1) mx = fmaxf(mx, __shfl_xor(mx, o));
  const float L2E = 1.4426950408889634f;
  float e[16], s = 0.f;
#pragma unroll
  for (int i = 0; i < 16; ++i) { e[i] = exp2f((l[i] - mx) * L2E); s += e[i]; }
#pragma unroll
  for (int o = 32; o > 0; o >>= 1) s += __shfl_xor(s, o);
  float inv = 1.0f / s;
  float4* o4 = reinterpret_cast<float4*>(out + row * S_DIM);
#pragma unroll
  for (int i = 0; i < 4; ++i)
    o4[lane * 4 + i] = make_float4(e[4*i]*inv, e[4*i+1]*inv, e[4*i+2]*inv, e[4*i+3]*inv);
}

extern "C" void kernel_launch(void* const* d_in, const int* in_sizes, int n_in,
                              void* d_out, int out_size, void* d_ws, size_t ws_size,
                              hipStream_t stream) {
  const float* x = (const float*)d_in[0];
  const float* gamma = (const float*)d_in[1];
  float* out = (float*)d_out;
  double* sums = (double*)d_ws;                              // 2 doubles @0
  float* sq = (float*)((char*)d_ws + 256);                   // 16384 floats
  ushort* xb16 = (ushort*)((char*)d_ws + 256 + 65536);       // 16 MB bf16 x
  _Float16* dp = (_Float16*)((char*)d_ws + 256 + 65536 +
                             (size_t)NBATCH * S_DIM * E_DIM * 2);  // 32 MB fp16 d'
  const size_t need_b = 256 + 65536 + (size_t)NBATCH * S_DIM * E_DIM * 2;
  const size_t need_a = need_b + (size_t)NBATCH * S_DIM * S_DIM * 2;

  sqcvt<<<dim3(NBATCH * S_DIM / 4), dim3(256), 0, stream>>>(x, xb16, sq, sums);
  if (ws_size >= need_a) {
    gram4<1><<<dim3(NBATCH * 64), dim3(256), 0, stream>>>(xb16, sq, out, dp, sums);
    softmax_f16<<<dim3(NBATCH * S_DIM / 4), dim3(256), 0, stream>>>(dp, out, sums, gamma);
  } else {
    gram4<0><<<dim3(NBATCH * 64), dim3(256), 0, stream>>>(xb16, sq, out, dp, sums);
    softmax_f32<<<dim3(NBATCH * S_DIM / 4), dim3(256), 0, stream>>>(out, sums, gamma);
  }
}

// Round 7
// 144.416 us; speedup vs baseline: 1.0995x; 1.0986x over previous
//
#include <hip/hip_runtime.h>
#include <hip/hip_bf16.h>

// x (16,1024,512) fp32 -> d = max(0, sq_i+sq_j-2*X X^T) per batch
// -> global-mean/var LayerNorm -> softmax(-(d_hat*gamma+beta)/TEMP, axis=-1).
// Softmax shift-invariance => mean & beta cancel; only
// scale = gamma*rsqrt(var+eps)/TEMP survives. var needs global sum(d),sum(d^2)
// in f64. Row-shift-invariance => store d' = d - sq_row as fp16.
//
// gram5: 256x256 tile, 8 waves (2x4), 512 threads, grid=256 = 1 block/CU.
// One prologue + one epilogue per CU (was 4 rounds of each at 128^2).
// Depth-2 prefetch, 3 LDS buffers (96KB), counted vmcnt(4), raw s_barrier.

#define S_DIM 1024
#define E_DIM 512
#define NBATCH 16
#define NSTEP (E_DIM / 32)
#define TEMP_C 13.544

typedef __attribute__((ext_vector_type(4))) float f32x4;
typedef __attribute__((ext_vector_type(8))) short bf16x8;
typedef __attribute__((ext_vector_type(8))) _Float16 f16x8;

__device__ inline unsigned pkbf(float lo, float hi) {
  unsigned a = __float_as_uint(lo), b = __float_as_uint(hi);
  a = (a + 0x7FFFu + ((a >> 16) & 1u)) >> 16;          // RNE bf16 of lo
  b = (b + 0x7FFFu + ((b >> 16) & 1u)) & 0xFFFF0000u;  // RNE bf16 of hi << 16
  return b | a;
}

__device__ inline void gload16(const void* g, void* l) {
  __builtin_amdgcn_global_load_lds(
      (const __attribute__((address_space(1))) unsigned*)g,
      (__attribute__((address_space(3))) unsigned*)l, 16, 0, 0);
}

// ---------------- Kernel 1: fp32->bf16 convert + row square-sums ------------
__global__ __launch_bounds__(256) void sqcvt(const float* __restrict__ x,
                                             ushort* __restrict__ xb16,
                                             float* __restrict__ sq,
                                             double* __restrict__ sums) {
  const int wave = threadIdx.x >> 6, lane = threadIdx.x & 63;
  const size_t row = (size_t)blockIdx.x * 4 + wave;
  const float4* xr = reinterpret_cast<const float4*>(x + row * E_DIM);
  float4 a = xr[lane * 2], b = xr[lane * 2 + 1];
  uint4 p;
  p.x = pkbf(a.x, a.y); p.y = pkbf(a.z, a.w);
  p.z = pkbf(b.x, b.y); p.w = pkbf(b.z, b.w);
  *reinterpret_cast<uint4*>(xb16 + row * E_DIM + lane * 8) = p;
  float s = a.x*a.x + a.y*a.y + a.z*a.z + a.w*a.w +
            b.x*b.x + b.y*b.y + b.z*b.z + b.w*b.w;
#pragma unroll
  for (int o = 32; o > 0; o >>= 1) s += __shfl_xor(s, o);
  if (lane == 0) sq[row] = s;
  if (blockIdx.x == 0 && threadIdx.x == 0) { sums[0] = 0.0; sums[1] = 0.0; }
}

// ------- Kernel 2: 256^2-tile gram, 8 waves, depth-2 counted-vmcnt ----------
// Wave (wr,wc): wr=wave>>2 (2 rows of 128), wc=wave&3 (4 cols of 64).
// Per wave per step: 8 A-frags + 4 B-frags (ds_read_b128), 32 MFMA 16x16x32.
// LDS: logical (row 0..255, slot s 0..3 of 8 bf16) at phys slot
// row*4 + (s ^ ((row>>1)&3))  -> conflict-free reads (verified: 0 conflicts).
// MODE 0: d fp32 -> dout.  MODE 1: d' = d - sq_row fp16 -> dp.
template <int MODE>
__global__ __launch_bounds__(512, 2) void gram5(const ushort* __restrict__ xb16,
                                                const float* __restrict__ sq,
                                                float* __restrict__ dout,
                                                _Float16* __restrict__ dp,
                                                double* __restrict__ sums) {
  __shared__ ushort lA[3][8192];   // 16KB per buffer
  __shared__ ushort lB[3][8192];
  __shared__ double red[16];

  const int tid = threadIdx.x, wave = tid >> 6, lane = tid & 63;
  const int wr = wave >> 2, wc = wave & 3;

  // 1 block/CU; 32 blocks/XCD; 2 batches per XCD (2MB bf16 L2-resident).
  const int bid = blockIdx.x;
  const int xcd = bid & 7, j = bid >> 3;            // j = 0..31
  const int b = xcd * 2 + (j >> 4);
  const int tile = j & 15;
  const int tr = tile >> 2, tc = tile & 3;

  const ushort* xb = xb16 + (size_t)b * (S_DIM * E_DIM);
  const int rowA0 = tr * 256, rowB0 = tc * 256;

  // Pre-swizzled per-lane global element offsets; LDS dest linear.
  // Thread covers phys slots p = i*512 + tid  (i=0,1) of each 16KB buffer.
  int eA[2], eB[2];
#pragma unroll
  for (int i = 0; i < 2; ++i) {
    int p = i * 512 + tid;
    int r = p >> 2;
    int s = (p & 3) ^ ((r >> 1) & 3);
    eA[i] = (rowA0 + r) * E_DIM + s * 8;
    eB[i] = (rowB0 + r) * E_DIM + s * 8;
  }

  auto stage = [&](int buf, int k0) {
    char* la = (char*)&lA[buf][0];
    char* lb = (char*)&lB[buf][0];
    gload16(xb + eA[0] + k0, la + (wave * 64 + lane) * 16);
    gload16(xb + eA[1] + k0, la + 8192 + (wave * 64 + lane) * 16);
    gload16(xb + eB[0] + k0, lb + (wave * 64 + lane) * 16);
    gload16(xb + eB[1] + k0, lb + 8192 + (wave * 64 + lane) * 16);
  };

  f32x4 acc[8][4] = {};

  stage(0, 0);
  stage(1, 32);
  int cur = 0;
#pragma unroll 1
  for (int ks = 0; ks < NSTEP; ++ks) {
    if (ks < NSTEP - 1) {
      asm volatile("s_waitcnt vmcnt(4)" ::: "memory");   // own stage(k) landed
    } else {
      asm volatile("s_waitcnt vmcnt(0)" ::: "memory");
    }
    __builtin_amdgcn_s_barrier();     // all stage(k) in LDS; iter k-1 reads done
    __builtin_amdgcn_sched_barrier(0);
    if (ks + 2 < NSTEP) {
      int nb = cur + 2; if (nb >= 3) nb -= 3;
      stage(nb, (ks + 2) * 32);       // WAR-safe: consumed at iter k-1
    }
    __builtin_amdgcn_sched_barrier(0);

    bf16x8 af[8], bfr[4];
    const int s0 = lane >> 4;
    const char* la = (const char*)&lA[cur][0];
    const char* lb = (const char*)&lB[cur][0];
#pragma unroll
    for (int m = 0; m < 8; ++m) {
      int row = wr * 128 + m * 16 + (lane & 15);
      af[m] = *reinterpret_cast<const bf16x8*>(la + row * 64 + ((s0 ^ ((row >> 1) & 3)) << 4));
    }
#pragma unroll
    for (int n = 0; n < 4; ++n) {
      int row = wc * 64 + n * 16 + (lane & 15);
      bfr[n] = *reinterpret_cast<const bf16x8*>(lb + row * 64 + ((s0 ^ ((row >> 1) & 3)) << 4));
    }
#pragma unroll
    for (int m = 0; m < 8; ++m)
#pragma unroll
      for (int n = 0; n < 4; ++n)
        acc[m][n] = __builtin_amdgcn_mfma_f32_16x16x32_bf16(af[m], bfr[n], acc[m][n], 0, 0, 0);

    if (++cur >= 3) cur = 0;
  }

  // Epilogue. C/D layout: col=lane&15, row=(lane>>4)*4+reg.
  const float* sqb = sq + b * S_DIM;
  double sd = 0.0, sd2 = 0.0;
#pragma unroll
  for (int m = 0; m < 8; ++m) {
    int gr0 = tr * 256 + wr * 128 + m * 16 + ((lane >> 4) << 2);
    float sqr0 = sqb[gr0], sqr1 = sqb[gr0 + 1], sqr2 = sqb[gr0 + 2], sqr3 = sqb[gr0 + 3];
#pragma unroll
    for (int n = 0; n < 4; ++n) {
      int gc = tc * 256 + wc * 64 + n * 16 + (lane & 15);
      float sqc = sqb[gc];
      float d0 = fmaxf(sqr0 + sqc - 2.0f * acc[m][n][0], 0.0f);
      float d1 = fmaxf(sqr1 + sqc - 2.0f * acc[m][n][1], 0.0f);
      float d2 = fmaxf(sqr2 + sqc - 2.0f * acc[m][n][2], 0.0f);
      float d3 = fmaxf(sqr3 + sqc - 2.0f * acc[m][n][3], 0.0f);
      if (MODE == 0) {
        float* dbase = dout + (size_t)b * S_DIM * S_DIM;
        dbase[(size_t)(gr0 + 0) * S_DIM + gc] = d0;
        dbase[(size_t)(gr0 + 1) * S_DIM + gc] = d1;
        dbase[(size_t)(gr0 + 2) * S_DIM + gc] = d2;
        dbase[(size_t)(gr0 + 3) * S_DIM + gc] = d3;
      } else {
        _Float16* dbase = dp + (size_t)b * S_DIM * S_DIM;
        dbase[(size_t)(gr0 + 0) * S_DIM + gc] = (_Float16)(d0 - sqr0);
        dbase[(size_t)(gr0 + 1) * S_DIM + gc] = (_Float16)(d1 - sqr1);
        dbase[(size_t)(gr0 + 2) * S_DIM + gc] = (_Float16)(d2 - sqr2);
        dbase[(size_t)(gr0 + 3) * S_DIM + gc] = (_Float16)(d3 - sqr3);
      }
      sd += (double)d0 + (double)d1 + (double)d2 + (double)d3;
      sd2 += (double)d0 * d0 + (double)d1 * d1 + (double)d2 * d2 + (double)d3 * d3;
    }
  }
#pragma unroll
  for (int o = 32; o > 0; o >>= 1) {
    sd += __shfl_xor(sd, o);
    sd2 += __shfl_xor(sd2, o);
  }
  if (lane == 0) { red[wave] = sd; red[8 + wave] = sd2; }
  __syncthreads();
  if (tid == 0) {
    double t1 = 0.0, t2 = 0.0;
#pragma unroll
    for (int w = 0; w < 8; ++w) { t1 += red[w]; t2 += red[8 + w]; }
    atomicAdd(&sums[0], t1);
    atomicAdd(&sums[1], t2);
  }
}

__device__ inline float ln_scale(const double* sums, const float* gamma) {
  constexpr double invN = 1.0 / (16.0 * 1024.0 * 1024.0);
  double mean = sums[0] * invN;
  double var = sums[1] * invN - mean * mean;
  return (float)(-((double)gamma[0]) / (sqrt(var + 1e-5) * TEMP_C));
}

// ---------------- Kernel 3a: softmax from fp32 d (in-place in dout) ---------
__global__ __launch_bounds__(256) void softmax_f32(float* __restrict__ d,
                                                   const double* __restrict__ sums,
                                                   const float* __restrict__ gamma) {
  const int wave = threadIdx.x >> 6, lane = threadIdx.x & 63;
  const size_t row = (size_t)blockIdx.x * 4 + wave;
  const float scale = ln_scale(sums, gamma);
  float4* r4 = reinterpret_cast<float4*>(d + row * S_DIM);
  float4 v[4];
#pragma unroll
  for (int i = 0; i < 4; ++i) v[i] = r4[lane + 64 * i];
  float l[16];
#pragma unroll
  for (int i = 0; i < 4; ++i) {
    l[4*i+0] = scale * v[i].x; l[4*i+1] = scale * v[i].y;
    l[4*i+2] = scale * v[i].z; l[4*i+3] = scale * v[i].w;
  }
  float mx = l[0];
#pragma unroll
  for (int i = 1; i < 16; ++i) mx = fmaxf(mx, l[i]);
#pragma unroll
  for (int o = 32; o > 0; o >>= 1) mx = fmaxf(mx, __shfl_xor(mx, o));
  const float L2E = 1.4426950408889634f;
  float e[16], s = 0.f;
#pragma unroll
  for (int i = 0; i < 16; ++i) { e[i] = exp2f((l[i] - mx) * L2E); s += e[i]; }
#pragma unroll
  for (int o = 32; o > 0; o >>= 1) s += __shfl_xor(s, o);
  float inv = 1.0f / s;
#pragma unroll
  for (int i = 0; i < 4; ++i)
    r4[lane + 64 * i] = make_float4(e[4*i]*inv, e[4*i+1]*inv, e[4*i+2]*inv, e[4*i+3]*inv);
}

// ---------------- Kernel 3b: softmax from fp16 d' (ws) -> fp32 out ----------
__global__ __launch_bounds__(256) void softmax_f16(const _Float16* __restrict__ dp,
                                                   float* __restrict__ out,
                                                   const double* __restrict__ sums,
                                                   const float* __restrict__ gamma) {
  const int wave = threadIdx.x >> 6, lane = threadIdx.x & 63;
  const size_t row = (size_t)blockIdx.x * 4 + wave;
  const float scale = ln_scale(sums, gamma);
  const f16x8* r8 = reinterpret_cast<const f16x8*>(dp + row * S_DIM);
  f16x8 h0 = r8[lane * 2], h1 = r8[lane * 2 + 1];
  float l[16];
#pragma unroll
  for (int i = 0; i < 8; ++i) { l[i] = scale * (float)h0[i]; l[8 + i] = scale * (float)h1[i]; }
  float mx = l[0];
#pragma unroll
  for (int i = 1; i < 16; ++i) mx = fmaxf(mx, l[i]);
#pragma unroll
  for (int o = 32; o > 0; o >>= 1) mx = fmaxf(mx, __shfl_xor(mx, o));
  const float L2E = 1.4426950408889634f;
  float e[16], s = 0.f;
#pragma unroll
  for (int i = 0; i < 16; ++i) { e[i] = exp2f((l[i] - mx) * L2E); s += e[i]; }
#pragma unroll
  for (int o = 32; o > 0; o >>= 1) s += __shfl_xor(s, o);
  float inv = 1.0f / s;
  float4* o4 = reinterpret_cast<float4*>(out + row * S_DIM);
#pragma unroll
  for (int i = 0; i < 4; ++i)
    o4[lane * 4 + i] = make_float4(e[4*i]*inv, e[4*i+1]*inv, e[4*i+2]*inv, e[4*i+3]*inv);
}

extern "C" void kernel_launch(void* const* d_in, const int* in_sizes, int n_in,
                              void* d_out, int out_size, void* d_ws, size_t ws_size,
                              hipStream_t stream) {
  const float* x = (const float*)d_in[0];
  const float* gamma = (const float*)d_in[1];
  float* out = (float*)d_out;
  double* sums = (double*)d_ws;                              // 2 doubles @0
  float* sq = (float*)((char*)d_ws + 256);                   // 16384 floats
  ushort* xb16 = (ushort*)((char*)d_ws + 256 + 65536);       // 16 MB bf16 x
  _Float16* dp = (_Float16*)((char*)d_ws + 256 + 65536 +
                             (size_t)NBATCH * S_DIM * E_DIM * 2);  // 32 MB fp16 d'
  const size_t need_b = 256 + 65536 + (size_t)NBATCH * S_DIM * E_DIM * 2;
  const size_t need_a = need_b + (size_t)NBATCH * S_DIM * S_DIM * 2;

  sqcvt<<<dim3(NBATCH * S_DIM / 4), dim3(256), 0, stream>>>(x, xb16, sq, sums);
  if (ws_size >= need_a) {
    gram5<1><<<dim3(256), dim3(512), 0, stream>>>(xb16, sq, out, dp, sums);
    softmax_f16<<<dim3(NBATCH * S_DIM / 4), dim3(256), 0, stream>>>(dp, out, sums, gamma);
  } else {
    gram5<0><<<dim3(256), dim3(512), 0, stream>>>(xb16, sq, out, dp, sums);
    softmax_f32<<<dim3(NBATCH * S_DIM / 4), dim3(256), 0, stream>>>(out, sums, gamma);
  }
}

// Round 8
// 143.320 us; speedup vs baseline: 1.1079x; 1.0077x over previous
//
#include <hip/hip_runtime.h>
#include <hip/hip_bf16.h>

// x (16,1024,512) fp32 -> d = max(0, sq_i+sq_j-2*X X^T) per batch
// -> global-mean/var LayerNorm -> softmax(-(d_hat*gamma+beta)/TEMP, axis=-1).
// Softmax shift-invariance => mean & beta cancel; only
// scale = gamma*rsqrt(var+eps)/TEMP survives. var needs global sum(d),sum(d^2)
// in f64. Row-shift-invariance => store d' = d - sq_row as fp16.
//
// gram6: 256x256 tile, 8 waves (2x4), grid=256 = 1 block/CU, BK=64 per
// barrier phase (8 phases instead of 16), double-buffered 128KB LDS,
// stage(k+1) issued BEFORE compute of k (loads in flight across the whole
// ~1200-cyc compute phase -> barrier vmcnt drain is latency-covered).

#define S_DIM 1024
#define E_DIM 512
#define NBATCH 16
#define NSTEP2 (E_DIM / 64)
#define TEMP_C 13.544

typedef __attribute__((ext_vector_type(4))) float f32x4;
typedef __attribute__((ext_vector_type(8))) short bf16x8;
typedef __attribute__((ext_vector_type(8))) _Float16 f16x8;

__device__ inline unsigned pkbf(float lo, float hi) {
  unsigned a = __float_as_uint(lo), b = __float_as_uint(hi);
  a = (a + 0x7FFFu + ((a >> 16) & 1u)) >> 16;          // RNE bf16 of lo
  b = (b + 0x7FFFu + ((b >> 16) & 1u)) & 0xFFFF0000u;  // RNE bf16 of hi << 16
  return b | a;
}

__device__ inline void gload16(const void* g, void* l) {
  __builtin_amdgcn_global_load_lds(
      (const __attribute__((address_space(1))) unsigned*)g,
      (__attribute__((address_space(3))) unsigned*)l, 16, 0, 0);
}

// ---------------- Kernel 1: fp32->bf16 convert + row square-sums ------------
__global__ __launch_bounds__(256) void sqcvt(const float* __restrict__ x,
                                             ushort* __restrict__ xb16,
                                             float* __restrict__ sq,
                                             double* __restrict__ sums) {
  const int wave = threadIdx.x >> 6, lane = threadIdx.x & 63;
  const size_t row = (size_t)blockIdx.x * 4 + wave;
  const float4* xr = reinterpret_cast<const float4*>(x + row * E_DIM);
  float4 a = xr[lane * 2], b = xr[lane * 2 + 1];
  uint4 p;
  p.x = pkbf(a.x, a.y); p.y = pkbf(a.z, a.w);
  p.z = pkbf(b.x, b.y); p.w = pkbf(b.z, b.w);
  *reinterpret_cast<uint4*>(xb16 + row * E_DIM + lane * 8) = p;
  float s = a.x*a.x + a.y*a.y + a.z*a.z + a.w*a.w +
            b.x*b.x + b.y*b.y + b.z*b.z + b.w*b.w;
#pragma unroll
  for (int o = 32; o > 0; o >>= 1) s += __shfl_xor(s, o);
  if (lane == 0) sq[row] = s;
  if (blockIdx.x == 0 && threadIdx.x == 0) { sums[0] = 0.0; sums[1] = 0.0; }
}

// ------- Kernel 2: 256^2-tile gram, 8 waves, BK=64 per barrier phase --------
// Wave (wr,wc): wr=wave>>2 (2 rows of 128), wc=wave&3 (4 cols of 64).
// LDS per buffer: A,B each [2 chunks][256 rows][32 cols] with per-chunk
// XOR-swizzle (slot s ^ ((row>>1)&3) on 16B units) -> conflict-free (0 meas).
// Per phase per wave: 24 ds_read_b128 + 64 MFMA 16x16x32 (2 chunks of K=32).
// MODE 0: d fp32 -> dout.  MODE 1: d' = d - sq_row fp16 -> dp.
template <int MODE>
__global__ __launch_bounds__(512, 2) void gram6(const ushort* __restrict__ xb16,
                                                const float* __restrict__ sq,
                                                float* __restrict__ dout,
                                                _Float16* __restrict__ dp,
                                                double* __restrict__ sums) {
  __shared__ ushort lA[2][2][8192];   // [buf][chunk][16KB]
  __shared__ ushort lB[2][2][8192];
  __shared__ double red[16];

  const int tid = threadIdx.x, wave = tid >> 6, lane = tid & 63;
  const int wr = wave >> 2, wc = wave & 3;

  // 1 block/CU; 32 blocks/XCD; 2 batches per XCD (2MB bf16 slab).
  const int bid = blockIdx.x;
  const int xcd = bid & 7, j = bid >> 3;            // j = 0..31
  const int b = xcd * 2 + (j >> 4);
  const int tile = j & 15;
  const int tr = tile >> 2, tc = tile & 3;

  const ushort* xb = xb16 + (size_t)b * (S_DIM * E_DIM);
  const int rowA0 = tr * 256, rowB0 = tc * 256;

  // Pre-swizzled per-lane global element offsets; LDS dest linear.
  // Thread covers phys 16B slots p = i*512 + tid (i=0,1) of each 16KB chunk.
  int eA[2], eB[2];
#pragma unroll
  for (int i = 0; i < 2; ++i) {
    int p = i * 512 + tid;
    int r = p >> 2;
    int s = (p & 3) ^ ((r >> 1) & 3);
    eA[i] = (rowA0 + r) * E_DIM + s * 8;
    eB[i] = (rowB0 + r) * E_DIM + s * 8;
  }

  auto stage = [&](int buf, int k0) {   // k0 = phase base col (64-aligned)
#pragma unroll
    for (int c = 0; c < 2; ++c) {
      char* la = (char*)&lA[buf][c][0];
      char* lb = (char*)&lB[buf][c][0];
      gload16(xb + eA[0] + k0 + c * 32, la + tid * 16);
      gload16(xb + eA[1] + k0 + c * 32, la + 8192 + tid * 16);
      gload16(xb + eB[0] + k0 + c * 32, lb + tid * 16);
      gload16(xb + eB[1] + k0 + c * 32, lb + 8192 + tid * 16);
    }
  };

  f32x4 acc[8][4] = {};

  stage(0, 0);
  int buf = 0;
#pragma unroll 1
  for (int ks = 0; ks < NSTEP2; ++ks) {
    __syncthreads();                       // stage(ks) landed; prev reads done
    if (ks + 1 < NSTEP2) stage(buf ^ 1, (ks + 1) * 64);  // overlap whole phase
#pragma unroll
    for (int c = 0; c < 2; ++c) {
      bf16x8 af[8], bfr[4];
      const int s0 = lane >> 4;
      const char* la = (const char*)&lA[buf][c][0];
      const char* lb = (const char*)&lB[buf][c][0];
#pragma unroll
      for (int m = 0; m < 8; ++m) {
        int row = wr * 128 + m * 16 + (lane & 15);
        af[m] = *reinterpret_cast<const bf16x8*>(la + row * 64 + ((s0 ^ ((row >> 1) & 3)) << 4));
      }
#pragma unroll
      for (int n = 0; n < 4; ++n) {
        int row = wc * 64 + n * 16 + (lane & 15);
        bfr[n] = *reinterpret_cast<const bf16x8*>(lb + row * 64 + ((s0 ^ ((row >> 1) & 3)) << 4));
      }
#pragma unroll
      for (int m = 0; m < 8; ++m)
#pragma unroll
        for (int n = 0; n < 4; ++n)
          acc[m][n] = __builtin_amdgcn_mfma_f32_16x16x32_bf16(af[m], bfr[n], acc[m][n], 0, 0, 0);
    }
    buf ^= 1;
  }

  // Epilogue. C/D layout: col=lane&15, row=(lane>>4)*4+reg.
  const float* sqb = sq + b * S_DIM;
  double sd = 0.0, sd2 = 0.0;
#pragma unroll
  for (int m = 0; m < 8; ++m) {
    int gr0 = tr * 256 + wr * 128 + m * 16 + ((lane >> 4) << 2);
    float sqr0 = sqb[gr0], sqr1 = sqb[gr0 + 1], sqr2 = sqb[gr0 + 2], sqr3 = sqb[gr0 + 3];
#pragma unroll
    for (int n = 0; n < 4; ++n) {
      int gc = tc * 256 + wc * 64 + n * 16 + (lane & 15);
      float sqc = sqb[gc];
      float d0 = fmaxf(sqr0 + sqc - 2.0f * acc[m][n][0], 0.0f);
      float d1 = fmaxf(sqr1 + sqc - 2.0f * acc[m][n][1], 0.0f);
      float d2 = fmaxf(sqr2 + sqc - 2.0f * acc[m][n][2], 0.0f);
      float d3 = fmaxf(sqr3 + sqc - 2.0f * acc[m][n][3], 0.0f);
      if (MODE == 0) {
        float* dbase = dout + (size_t)b * S_DIM * S_DIM;
        dbase[(size_t)(gr0 + 0) * S_DIM + gc] = d0;
        dbase[(size_t)(gr0 + 1) * S_DIM + gc] = d1;
        dbase[(size_t)(gr0 + 2) * S_DIM + gc] = d2;
        dbase[(size_t)(gr0 + 3) * S_DIM + gc] = d3;
      } else {
        _Float16* dbase = dp + (size_t)b * S_DIM * S_DIM;
        dbase[(size_t)(gr0 + 0) * S_DIM + gc] = (_Float16)(d0 - sqr0);
        dbase[(size_t)(gr0 + 1) * S_DIM + gc] = (_Float16)(d1 - sqr1);
        dbase[(size_t)(gr0 + 2) * S_DIM + gc] = (_Float16)(d2 - sqr2);
        dbase[(size_t)(gr0 + 3) * S_DIM + gc] = (_Float16)(d3 - sqr3);
      }
      sd += (double)d0 + (double)d1 + (double)d2 + (double)d3;
      sd2 += (double)d0 * d0 + (double)d1 * d1 + (double)d2 * d2 + (double)d3 * d3;
    }
  }
#pragma unroll
  for (int o = 32; o > 0; o >>= 1) {
    sd += __shfl_xor(sd, o);
    sd2 += __shfl_xor(sd2, o);
  }
  if (lane == 0) { red[wave] = sd; red[8 + wave] = sd2; }
  __syncthreads();
  if (tid == 0) {
    double t1 = 0.0, t2 = 0.0;
#pragma unroll
    for (int w = 0; w < 8; ++w) { t1 += red[w]; t2 += red[8 + w]; }
    atomicAdd(&sums[0], t1);
    atomicAdd(&sums[1], t2);
  }
}

__device__ inline float ln_scale(const double* sums, const float* gamma) {
  constexpr double invN = 1.0 / (16.0 * 1024.0 * 1024.0);
  double mean = sums[0] * invN;
  double var = sums[1] * invN - mean * mean;
  return (float)(-((double)gamma[0]) / (sqrt(var + 1e-5) * TEMP_C));
}

// ---------------- Kernel 3a: softmax from fp32 d (in-place in dout) ---------
__global__ __launch_bounds__(256) void softmax_f32(float* __restrict__ d,
                                                   const double* __restrict__ sums,
                                                   const float* __restrict__ gamma) {
  const int wave = threadIdx.x >> 6, lane = threadIdx.x & 63;
  const size_t row = (size_t)blockIdx.x * 4 + wave;
  const float scale = ln_scale(sums, gamma);
  float4* r4 = reinterpret_cast<float4*>(d + row * S_DIM);
  float4 v[4];
#pragma unroll
  for (int i = 0; i < 4; ++i) v[i] = r4[lane + 64 * i];
  float l[16];
#pragma unroll
  for (int i = 0; i < 4; ++i) {
    l[4*i+0] = scale * v[i].x; l[4*i+1] = scale * v[i].y;
    l[4*i+2] = scale * v[i].z; l[4*i+3] = scale * v[i].w;
  }
  float mx = l[0];
#pragma unroll
  for (int i = 1; i < 16; ++i) mx = fmaxf(mx, l[i]);
#pragma unroll
  for (int o = 32; o > 0; o >>= 1) mx = fmaxf(mx, __shfl_xor(mx, o));
  const float L2E = 1.4426950408889634f;
  float e[16], s = 0.f;
#pragma unroll
  for (int i = 0; i < 16; ++i) { e[i] = exp2f((l[i] - mx) * L2E); s += e[i]; }
#pragma unroll
  for (int o = 32; o > 0; o >>= 1) s += __shfl_xor(s, o);
  float inv = 1.0f / s;
#pragma unroll
  for (int i = 0; i < 4; ++i)
    r4[lane + 64 * i] = make_float4(e[4*i]*inv, e[4*i+1]*inv, e[4*i+2]*inv, e[4*i+3]*inv);
}

// ---------------- Kernel 3b: softmax from fp16 d' (ws) -> fp32 out ----------
__global__ __launch_bounds__(256) void softmax_f16(const _Float16* __restrict__ dp,
                                                   float* __restrict__ out,
                                                   const double* __restrict__ sums,
                                                   const float* __restrict__ gamma) {
  const int wave = threadIdx.x >> 6, lane = threadIdx.x & 63;
  const size_t row = (size_t)blockIdx.x * 4 + wave;
  const float scale = ln_scale(sums, gamma);
  const f16x8* r8 = reinterpret_cast<const f16x8*>(dp + row * S_DIM);
  f16x8 h0 = r8[lane * 2], h1 = r8[lane * 2 + 1];
  float l[16];
#pragma unroll
  for (int i = 0; i < 8; ++i) { l[i] = scale * (float)h0[i]; l[8 + i] = scale * (float)h1[i]; }
  float mx = l[0];
#pragma unroll
  for (int i = 1; i < 16; ++i) mx = fmaxf(mx, l[i]);
#pragma unroll
  for (int o = 32; o > 0; o >>= 1) mx = fmaxf(mx, __shfl_xor(mx, o));
  const float L2E = 1.4426950408889634f;
  float e[16], s = 0.f;
#pragma unroll
  for (int i = 0; i < 16; ++i) { e[i] = exp2f((l[i] - mx) * L2E); s += e[i]; }
#pragma unroll
  for (int o = 32; o > 0; o >>= 1) s += __shfl_xor(s, o);
  float inv = 1.0f / s;
  float4* o4 = reinterpret_cast<float4*>(out + row * S_DIM);
#pragma unroll
  for (int i = 0; i < 4; ++i)
    o4[lane * 4 + i] = make_float4(e[4*i]*inv, e[4*i+1]*inv, e[4*i+2]*inv, e[4*i+3]*inv);
}

extern "C" void kernel_launch(void* const* d_in, const int* in_sizes, int n_in,
                              void* d_out, int out_size, void* d_ws, size_t ws_size,
                              hipStream_t stream) {
  const float* x = (const float*)d_in[0];
  const float* gamma = (const float*)d_in[1];
  float* out = (float*)d_out;
  double* sums = (double*)d_ws;                              // 2 doubles @0
  float* sq = (float*)((char*)d_ws + 256);                   // 16384 floats
  ushort* xb16 = (ushort*)((char*)d_ws + 256 + 65536);       // 16 MB bf16 x
  _Float16* dp = (_Float16*)((char*)d_ws + 256 + 65536 +
                             (size_t)NBATCH * S_DIM * E_DIM * 2);  // 32 MB fp16 d'
  const size_t need_b = 256 + 65536 + (size_t)NBATCH * S_DIM * E_DIM * 2;
  const size_t need_a = need_b + (size_t)NBATCH * S_DIM * S_DIM * 2;

  sqcvt<<<dim3(NBATCH * S_DIM / 4), dim3(256), 0, stream>>>(x, xb16, sq, sums);
  if (ws_size >= need_a) {
    gram6<1><<<dim3(256), dim3(512), 0, stream>>>(xb16, sq, out, dp, sums);
    softmax_f16<<<dim3(NBATCH * S_DIM / 4), dim3(256), 0, stream>>>(dp, out, sums, gamma);
  } else {
    gram6<0><<<dim3(256), dim3(512), 0, stream>>>(xb16, sq, out, dp, sums);
    softmax_f32<<<dim3(NBATCH * S_DIM / 4), dim3(256), 0, stream>>>(out, sums, gamma);
  }
}